// Round 3
// 419.255 us; speedup vs baseline: 1.0224x; 1.0224x over previous
//
#include <hip/hip_runtime.h>

#define B_DIM 4096
#define IN_DIM 8192
#define HID_DIM 8192

// Native clang vector type — __builtin_nontemporal_load requires it
// (HIP_vector_type float4 is a struct and is rejected).
typedef float floatx4 __attribute__((ext_vector_type(4)));

// Zero the w_sum accumulator in workspace (d_ws is re-poisoned to 0xAA).
__global__ void zero_kernel(float* __restrict__ w) {
    int i = blockIdx.x * blockDim.x + threadIdx.x;
    if (i < IN_DIM) w[i] = 0.0f;
}

// Column sums of weight [HID, IN] (row-major) -> w_sum [IN].
// grid: (IN/(256*4), HID/ROWS_PER_BLOCK) = (8, 256) = 2048 blocks
//   -> 8 blocks/CU on 256 CUs = 32 waves/CU (max occupancy).
// Each thread owns 4 consecutive columns (one float4 lane), accumulates
// ROWS_PER_BLOCK rows locally, then contributes via 4 fp32 atomics.
#define ROWS_PER_BLOCK 32
__global__ void __launch_bounds__(256, 8)
colsum_kernel(const float* __restrict__ W, float* __restrict__ w_sum) {
    const int col4 = blockIdx.x * blockDim.x + threadIdx.x;   // float4 column index
    const int row0 = blockIdx.y * ROWS_PER_BLOCK;
    const int stride4 = IN_DIM / 4;
    const floatx4* __restrict__ p = (const floatx4*)W + (size_t)row0 * stride4 + col4;

    floatx4 acc = (floatx4)(0.f);
#pragma unroll 8
    for (int r = 0; r < ROWS_PER_BLOCK; ++r) {
        floatx4 v = __builtin_nontemporal_load(&p[(size_t)r * stride4]);
        acc += v;
    }
    const int col = col4 * 4;
    atomicAdd(&w_sum[col + 0], acc.x);
    atomicAdd(&w_sum[col + 1], acc.y);
    atomicAdd(&w_sum[col + 2], acc.z);
    atomicAdd(&w_sum[col + 3], acc.w);
}

// GEMV: out[b] = 0.75 * sum_i x[b,i] * w_sum[i].
// One wave (64 lanes) per row of x; float4 loads, shuffle reduction.
// 1024 blocks x 256 threads = 4 blocks/CU, 16 waves/CU.
__global__ void __launch_bounds__(256, 4)
gemv_kernel(const float* __restrict__ x,
            const float* __restrict__ w_sum,
            float* __restrict__ out) {
    const int wave = (int)((blockIdx.x * blockDim.x + threadIdx.x) >> 6);
    const int lane = threadIdx.x & 63;
    if (wave >= B_DIM) return;

    const floatx4* __restrict__ xr  = (const floatx4*)(x + (size_t)wave * IN_DIM);
    const floatx4* __restrict__ ws4 = (const floatx4*)w_sum;

    float acc = 0.f;
#pragma unroll 8
    for (int i = lane; i < IN_DIM / 4; i += 64) {
        floatx4 xv = __builtin_nontemporal_load(&xr[i]);  // x read once; keep L2 for w_sum
        floatx4 wv = ws4[i];
        acc += xv.x * wv.x + xv.y * wv.y + xv.z * wv.z + xv.w * wv.w;
    }
#pragma unroll
    for (int off = 32; off > 0; off >>= 1)
        acc += __shfl_down(acc, off);

    if (lane == 0) out[wave] = acc * 0.75f;
}

extern "C" void kernel_launch(void* const* d_in, const int* in_sizes, int n_in,
                              void* d_out, int out_size, void* d_ws, size_t ws_size,
                              hipStream_t stream) {
    const float* x = (const float*)d_in[0];   // [B, IN]
    const float* W = (const float*)d_in[1];   // [HID, IN]
    float* out = (float*)d_out;               // [B, 1]
    float* w_sum = (float*)d_ws;              // [IN] scratch

    zero_kernel<<<IN_DIM / 256, 256, 0, stream>>>(w_sum);

    dim3 g1(IN_DIM / (256 * 4), HID_DIM / ROWS_PER_BLOCK);
    colsum_kernel<<<g1, 256, 0, stream>>>(W, w_sum);

    // 4096 waves, 4 waves per 256-thread block -> 1024 blocks
    gemv_kernel<<<B_DIM / 4, 256, 0, stream>>>(x, w_sum, out);
}